// Round 1
// baseline (71.348 us; speedup 1.0000x reference)
//
#include <hip/hip_runtime.h>
#include <math.h>

// CropProposals: 3D ROI adaptive 2x2x2 max-pool.
// fm: (4,64,24,24,24) f32, corners: (4,64,2,3) f32 -> out: (4,64,64,2,2,2) f32
//
// One wave (64 threads) per (b, n, c). Lanes are split 8 bins x 8 sub-lanes:
// bin = lane>>3 encodes (kx,ky,kz); sub = lane&7 strides the bin's voxels.
// Bins can OVERLAP (reference uses bin_hi = lo + ((k+1)*n+1)//2, bin_lo =
// lo + k*n//2, overlapping by one slab when n odd), so each bin reduces its
// own range independently.

#define FM_CH 13824  // 24*24*24

__global__ __launch_bounds__(64) void crop_pool_kernel(
    const float* __restrict__ fm,
    const float* __restrict__ corners,
    float* __restrict__ out)
{
    const int idx  = blockIdx.x;      // ((b*64 + n)*64 + c)
    const int c    = idx & 63;
    const int bn   = idx >> 6;        // b*64 + n
    const int b    = bn >> 6;
    const int lane = threadIdx.x;     // 0..63
    const int bin  = lane >> 3;       // 0..7  == kx*4 + ky*2 + kz
    const int sub  = lane & 7;        // 0..7
    const int kx = (bin >> 2) & 1;
    const int ky = (bin >> 1) & 1;
    const int kz =  bin       & 1;

    // Per-axis lo / n, exactly mirroring the reference fp32 arithmetic.
    int lo[3], nn[3];
#pragma unroll
    for (int a = 0; a < 3; ++a) {
        float LL = corners[bn * 6 + a] * 0.25f;
        LL = fminf(fmaxf(LL, 0.0f), 21.0f);
        float UR = corners[bn * 6 + 3 + a] * 0.25f;
        UR = (UR - LL >= 2.0f) ? UR : (LL + 2.0f);
        UR = fminf(fmaxf(UR, 2.0f), 23.0f);
        lo[a] = (int)floorf(LL);
        nn[a] = (int)floorf(UR) - lo[a];   // >= 2 always
    }

    // This lane's bin ranges. k*n//2 and ((k+1)*n+1)//2 with k,n >= 0.
    const int ks[3] = {kx, ky, kz};
    int s0[3], s1[3];
#pragma unroll
    for (int a = 0; a < 3; ++a) {
        s0[a] = lo[a] + ((ks[a] * nn[a]) >> 1);
        s1[a] = lo[a] + (((ks[a] + 1) * nn[a] + 1) >> 1);
    }
    const int ny  = s1[1] - s0[1];
    const int nz  = s1[2] - s0[2];
    const int vol = (s1[0] - s0[0]) * ny * nz;

    const float* fmb = fm + (size_t)(b * 64 + c) * FM_CH;

    float m = -INFINITY;
    for (int i = sub; i < vol; i += 8) {
        int z = i % nz;
        int t = i / nz;
        int y = t % ny;
        int x = t / ny;
        m = fmaxf(m, fmb[((s0[0] + x) * 24 + (s0[1] + y)) * 24 + (s0[2] + z)]);
    }

    // Reduce within the 8-lane sub-group (xor offsets 1,2,4 stay in-group).
#pragma unroll
    for (int off = 1; off < 8; off <<= 1)
        m = fmaxf(m, __shfl_xor(m, off));

    if (sub == 0)
        out[idx * 8 + bin] = m;
}

extern "C" void kernel_launch(void* const* d_in, const int* in_sizes, int n_in,
                              void* d_out, int out_size, void* d_ws, size_t ws_size,
                              hipStream_t stream)
{
    const float* fm      = (const float*)d_in[0];
    const float* corners = (const float*)d_in[1];
    float* out           = (float*)d_out;

    // grid = B*N*C = 4*64*64 = 16384 waves, one per output octet.
    crop_pool_kernel<<<16384, 64, 0, stream>>>(fm, corners, out);
}

// Round 2
// 69.943 us; speedup vs baseline: 1.0201x; 1.0201x over previous
//
#include <hip/hip_runtime.h>
#include <math.h>

// CropProposals: 3D ROI adaptive 2x2x2 max-pool.
// fm: (4,64,24,24,24) f32, corners: (4,64,2,3) f32 -> out: (4,64,64,2,2,2) f32
//
// One wave per (b,c,n) triple (n fastest so consecutive waves share a 54KB
// channel volume -> L1/L2 reuse). Lanes split 8 bins x 8 sub-lanes. Bins may
// OVERLAP (bin_hi = lo+((k+1)*n+1)//2, bin_lo = lo+k*n//2), so each bin
// reduces its own range. Inner loop uses exact magic-multiply division
// (M = 2^19/d + 1; exact because i*d <= 1727*12 < 2^19) instead of the
// ~15-instruction runtime div macro, and 4 independent max accumulators to
// keep 4 gather loads in flight on the big-box tail waves.

#define FM_CH 13824  // 24*24*24

__global__ __launch_bounds__(256) void crop_pool_kernel(
    const float* __restrict__ fm,
    const float* __restrict__ corners,
    float* __restrict__ out)
{
    const int lane = threadIdx.x & 63;
    const int w    = blockIdx.x * 4 + (threadIdx.x >> 6);  // 0..16383, (b,c,n)
    const int n = w & 63;
    const int c = (w >> 6) & 63;
    const int b = w >> 12;
    const int bn = b * 64 + n;

    const int bin = lane >> 3;   // kx*4 + ky*2 + kz
    const int sub = lane & 7;
    const int ks[3] = { (bin >> 2) & 1, (bin >> 1) & 1, bin & 1 };

    // Per-axis bin range, exactly mirroring the reference fp32 arithmetic.
    int s0[3], s1[3];
#pragma unroll
    for (int a = 0; a < 3; ++a) {
        float LL = corners[bn * 6 + a] * 0.25f;
        LL = fminf(fmaxf(LL, 0.0f), 21.0f);
        float UR = corners[bn * 6 + 3 + a] * 0.25f;
        UR = (UR - LL >= 2.0f) ? UR : (LL + 2.0f);
        UR = fminf(fmaxf(UR, 2.0f), 23.0f);
        int lo = (int)floorf(LL);
        int nn = (int)floorf(UR) - lo;              // 2..23
        s0[a] = lo + ((ks[a] * nn) >> 1);
        s1[a] = lo + (((ks[a] + 1) * nn + 1) >> 1);
    }
    const unsigned ny  = (unsigned)(s1[1] - s0[1]);  // 1..12
    const unsigned nz  = (unsigned)(s1[2] - s0[2]);  // 1..12
    const unsigned vol = (unsigned)(s1[0] - s0[0]) * ny * nz;  // <= 1728

    // Exact magic division: q = (i*M) >> 19 == i/d for i*d < 2^19.
    const unsigned Mz = (1u << 19) / nz + 1;
    const unsigned My = (1u << 19) / ny + 1;

    const float* base = fm + (size_t)(b * 64 + c) * FM_CH
                           + ((s0[0] * 24 + s0[1]) * 24 + s0[2]);

    auto voxel = [&](unsigned i) -> float {
        unsigned q = (i * Mz) >> 19;       // q = x*ny + y
        unsigned z = i - q * nz;
        unsigned x = (q * My) >> 19;
        unsigned y = q - x * ny;
        return base[x * 576u + y * 24u + z];
    };

    float m0 = -INFINITY, m1 = -INFINITY, m2 = -INFINITY, m3 = -INFINITY;
    unsigned i = sub;
    for (; i + 24 < vol; i += 32) {        // 4 loads in flight
        m0 = fmaxf(m0, voxel(i));
        m1 = fmaxf(m1, voxel(i + 8));
        m2 = fmaxf(m2, voxel(i + 16));
        m3 = fmaxf(m3, voxel(i + 24));
    }
    for (; i < vol; i += 8)
        m0 = fmaxf(m0, voxel(i));
    float m = fmaxf(fmaxf(m0, m1), fmaxf(m2, m3));

    // Reduce within the 8-lane sub-group (xor offsets 1,2,4 stay in-group).
#pragma unroll
    for (int off = 1; off < 8; off <<= 1)
        m = fmaxf(m, __shfl_xor(m, off));

    // Funnel the 8 bin maxes to lanes 0..7 -> one coalesced 32B store/wave.
    float v = __shfl(m, (lane & 7) << 3);
    if (lane < 8)
        out[((size_t)(bn * 64 + c)) * 8 + lane] = v;
}

extern "C" void kernel_launch(void* const* d_in, const int* in_sizes, int n_in,
                              void* d_out, int out_size, void* d_ws, size_t ws_size,
                              hipStream_t stream)
{
    const float* fm      = (const float*)d_in[0];
    const float* corners = (const float*)d_in[1];
    float* out           = (float*)d_out;

    // 16384 waves, 4 per block.
    crop_pool_kernel<<<4096, 256, 0, stream>>>(fm, corners, out);
}